// Round 5
// baseline (736.820 us; speedup 1.0000x reference)
//
#include <hip/hip_runtime.h>
#include <math.h>

#define INV_SQRT2f 0.70710678118654752440f
#define SILU_SCALEf (1.0f / 0.6f)

typedef __attribute__((ext_vector_type(8))) short bf16x8;
typedef __attribute__((ext_vector_type(4))) float f32x4;

__device__ __forceinline__ float ssilu(float v) {
    return (v / (1.0f + __expf(-v))) * SILU_SCALEf;
}

__device__ __forceinline__ unsigned short f2bf(float f) {
    unsigned int u = __float_as_uint(f);
    unsigned int r = (u + 0x7FFFu + ((u >> 16) & 1u)) >> 16;
    return (unsigned short)r;
}

// ---------------------------------------------------------------------------
// Edge phase: counting-sort by atom (CSR) — unchanged (measured-good).
// ---------------------------------------------------------------------------
__global__ void zero_kernel(int* __restrict__ p, int n)
{
    int i = blockIdx.x * blockDim.x + threadIdx.x;
    for (; i < n; i += gridDim.x * blockDim.x) p[i] = 0;
}

__global__ void hist_kernel(const int* __restrict__ id_j, int* __restrict__ counts,
                            int nEdges)
{
    int i = blockIdx.x * blockDim.x + threadIdx.x;
    for (; i < nEdges; i += gridDim.x * blockDim.x)
        atomicAdd(&counts[id_j[i]], 1);
}

__global__ void scan_reduce(const int* __restrict__ counts, int* __restrict__ bsum,
                            int n)
{
    __shared__ int s[256];
    int base = blockIdx.x * 1024;
    int t = threadIdx.x;
    int v = 0;
#pragma unroll
    for (int k = 0; k < 4; ++k) {
        int i = base + t + k * 256;
        if (i < n) v += counts[i];
    }
    s[t] = v;
    __syncthreads();
    for (int off = 128; off > 0; off >>= 1) {
        if (t < off) s[t] += s[t + off];
        __syncthreads();
    }
    if (t == 0) bsum[blockIdx.x] = s[0];
}

// wave-parallel exclusive scan of chunk totals (single 64-thread block)
__global__ void scan_sums(int* __restrict__ bsum, int nb)
{
    int l = threadIdx.x & 63;
    int carry = 0;
    for (int base = 0; base < nb; base += 64) {
        int idx = base + l;
        int orig = (idx < nb) ? bsum[idx] : 0;
        int v = orig;
#pragma unroll
        for (int off = 1; off < 64; off <<= 1) {
            int u = __shfl_up(v, off, 64);
            if (l >= off) v += u;
        }
        if (idx < nb) bsum[idx] = carry + v - orig;
        carry += __shfl(v, 63, 64);
    }
}

__global__ void scan_write(const int* __restrict__ counts, const int* __restrict__ bsum,
                           int* __restrict__ offsets, int* __restrict__ cursor, int n)
{
    __shared__ int s[256];
    int base = blockIdx.x * 1024;
    int t = threadIdx.x;
    int v[4];
    int tot = 0;
#pragma unroll
    for (int k = 0; k < 4; ++k) {
        int i = base + t * 4 + k;
        int c = (i < n) ? counts[i] : 0;
        v[k] = tot; tot += c;
    }
    s[t] = tot;
    __syncthreads();
    for (int off = 1; off < 256; off <<= 1) {
        int x = (t >= off) ? s[t - off] : 0;
        __syncthreads();
        s[t] += x;
        __syncthreads();
    }
    int excl = (t > 0) ? s[t - 1] : 0;
    int bo = bsum[blockIdx.x];
#pragma unroll
    for (int k = 0; k < 4; ++k) {
        int i = base + t * 4 + k;
        if (i < n) { int o = bo + excl + v[k]; offsets[i] = o; cursor[i] = o; }
    }
}

__global__ void order_kernel(const int* __restrict__ id_j, int* __restrict__ cursor,
                             int* __restrict__ order, int nEdges)
{
    int i = blockIdx.x * blockDim.x + threadIdx.x;
    for (; i < nEdges; i += gridDim.x * blockDim.x) {
        int j = id_j[i];
        int p = atomicAdd(&cursor[j], 1);
        order[p] = i;
    }
}

// ---------------------------------------------------------------------------
// Weight conversion: f32 [256][256] row-major -> bf16 fragment-ordered blob.
// ---------------------------------------------------------------------------
__global__ void __launch_bounds__(256) wconv_kernel(
    const float* __restrict__ W1, const float* __restrict__ res_W,
    unsigned short* __restrict__ blob)
{
    __shared__ float ws[32][260];
    const int b = blockIdx.x;        // b = L*8 + c
    const int L = b >> 3, c = b & 7;
    const int t = threadIdx.x;
    const float* W = (L == 0) ? W1 : res_W + (size_t)(L - 1) * 65536;

#pragma unroll
    for (int r = 0; r < 32; ++r)
        ws[r][t] = W[(size_t)(c * 32 + r) * 256 + t];
    __syncthreads();

    unsigned short* dst = blob + (size_t)b * 8192;
#pragma unroll
    for (int q = 0; q < 32; ++q) {
        int flat = q * 256 + t;
        int jj = flat & 7, n = (flat >> 3) & 255, g = flat >> 11;
        dst[flat] = f2bf(ws[g * 8 + jj][n]);
    }
}

// ---------------------------------------------------------------------------
// Gather v5: deep-pipelined multi-atom DMA gather.
// Block = 4 waves, owns A=8 consecutive atoms = one CONTIGUOUS order[] range
// (~160 edges = ~10 chunks of 16). Quad-buffered LDS staging; stage runs 3
// chunks ahead with counted s_waitcnt vmcnt(10) (never 0) -> 15 m-row DMAs
// (48 KB) stay in flight per block across barriers. Edge ids staged to LDS
// once (id reads are lgkmcnt, keeping the vmcnt FIFO = exactly 5 DMAs per
// wave per chunk for clean counted waits). 2 blocks/CU (74 KB LDS) ->
// ~96 KB in flight per CU sustained.
// Consume walks atom segments with uniform scalar boundary compares, flushing
// f32 acc -> bf16 swizzled x2b image per atom.
// NOTE: ord_lds capacity 1024 edges/block; block edge-sum is Poisson(160)
// (68 sigma margin) for this harness's uniform id_j.
// ---------------------------------------------------------------------------
__global__ void __launch_bounds__(256, 2) gather_kernel(
    const float* __restrict__ m, const float* __restrict__ rbf,
    const int* __restrict__ order, const int* __restrict__ offsets,
    const int* __restrict__ counts, const float* __restrict__ W_rbf,
    unsigned short* __restrict__ x2b)
{
    constexpr int A = 8;
    __shared__ __align__(16) float mbuf[4][16][256];   // 64 KB
    __shared__ __align__(16) float rbuf[4][16][16];    // 4 KB
    __shared__ int ord_lds[1024];                      // 4 KB
    __shared__ int bnd_lds[A + 1];
    __shared__ int s_base;

    const int t = threadIdx.x;
    const int lane = t & 63;
    const int w = t >> 6;
    const int jb = blockIdx.x * A;

    float w16[16];
#pragma unroll
    for (int k = 0; k < 16; ++k) w16[k] = W_rbf[k * 256 + t];

    // --- prologue: segment boundaries + edge-id staging ---
    if (t < A) bnd_lds[t + 1] = counts[jb + t];
    if (t == 0) { s_base = offsets[jb]; bnd_lds[0] = 0; }
    __syncthreads();
    if (t == 0) {
#pragma unroll
        for (int q = 0; q < A; ++q) bnd_lds[q + 1] += bnd_lds[q];
    }
    __syncthreads();
    const int S = s_base;
    const int totE = bnd_lds[A];

    if (totE > 0) {
#pragma unroll
        for (int u = 0; u < 4; ++u) {
            int idx = t + u * 256;
            int cl = (idx < totE) ? idx : (totE - 1);
            ord_lds[idx] = order[S + cl];
        }
    }
    __syncthreads();   // drains vmcnt -> clean FIFO for the counted pipeline

#define STAGE(c_) do {                                                        \
    const int cc_ = (c_);                                                     \
    const int cs_ = cc_ * 16;                                                 \
    const int bsel_ = cc_ & 3;                                                \
    _Pragma("unroll")                                                         \
    for (int q_ = 0; q_ < 4; ++q_) {                                          \
        int sub_ = w * 4 + q_;                                                \
        int rp_ = cs_ + sub_; if (rp_ > totE - 1) rp_ = totE - 1;             \
        int e_ = ord_lds[rp_];                                                \
        const float* src_ = m + (size_t)e_ * 256 + lane * 4;                  \
        __builtin_amdgcn_global_load_lds(                                     \
            (const __attribute__((address_space(1))) unsigned int*)src_,      \
            (__attribute__((address_space(3))) unsigned int*)&mbuf[bsel_][sub_][0], \
            16, 0, 0);                                                        \
    }                                                                         \
    {                                                                         \
        int sub_ = w * 4 + (lane >> 4);                                       \
        int rp_ = cs_ + sub_; if (rp_ > totE - 1) rp_ = totE - 1;             \
        int e_ = ord_lds[rp_];                                                \
        const float* src_ = rbf + (size_t)e_ * 16 + (lane & 15);              \
        __builtin_amdgcn_global_load_lds(                                     \
            (const __attribute__((address_space(1))) unsigned int*)src_,      \
            (__attribute__((address_space(3))) unsigned int*)&rbuf[bsel_][w * 4][0], \
            4, 0, 0);                                                         \
    }                                                                         \
} while (0)

    const int K = (totE + 15) >> 4;
    float acc = 0.0f;
    int q = 0;
    int next_b = bnd_lds[1];

    if (K > 0) {
        STAGE(0);
        STAGE((K > 1) ? 1 : 0);
        STAGE((K > 2) ? 2 : (K - 1));

        for (int k = 0; k < K; ++k) {
            asm volatile("s_waitcnt vmcnt(10)" ::: "memory");
            __builtin_amdgcn_s_barrier();
            asm volatile("" ::: "memory");

            int nc = k + 3; if (nc > K - 1) nc = K - 1;
            STAGE(nc);    // dup-stages at tail land in dead buffers (safe)

            const float* mb = &mbuf[k & 3][0][0];
            const float* rb = &rbuf[k & 3][0][0];
            int cnt = totE - k * 16; if (cnt > 16) cnt = 16;
            for (int i = 0; i < cnt; ++i) {
                int p = k * 16 + i;
                while (p >= next_b) {           // uniform scalar branch
                    int j = jb + q;
                    int tile = j >> 6, r = j & 63;
                    x2b[(size_t)tile * 16384 + ((r * 256 + t) ^ ((r & 7) << 3))] = f2bf(acc);
                    acc = 0.0f;
                    ++q;
                    next_b = bnd_lds[q + 1];
                }
                float mv = mb[i * 256 + t];
                const float4* rp4 = reinterpret_cast<const float4*>(rb + i * 16);
                float4 a = rp4[0], b = rp4[1], c4 = rp4[2], d = rp4[3];
                float g = a.x*w16[0] + a.y*w16[1] + a.z*w16[2] + a.w*w16[3]
                        + b.x*w16[4] + b.y*w16[5] + b.z*w16[6] + b.w*w16[7]
                        + c4.x*w16[8] + c4.y*w16[9] + c4.z*w16[10] + c4.w*w16[11]
                        + d.x*w16[12] + d.y*w16[13] + d.z*w16[14] + d.w*w16[15];
                acc += mv * g;
            }
            asm volatile("" ::: "memory");
        }
    }

    // epilogue: flush remaining atoms (also handles all-empty blocks)
    while (q < A) {
        int j = jb + q;
        int tile = j >> 6, r = j & 63;
        x2b[(size_t)tile * 16384 + ((r * 256 + t) ^ ((r & 7) << 3))] = f2bf(acc);
        acc = 0.0f;
        ++q;
    }
#undef STAGE
}

// ---------------------------------------------------------------------------
// Dense chain, 8-wave variant (measured-good). Pure global->LDS DMA load of
// the pre-swizzled bf16 x2b image, then 7-layer MFMA chain.
// ---------------------------------------------------------------------------
__global__ void __launch_bounds__(512) dense_kernel(
    const unsigned short* __restrict__ x2b, const unsigned short* __restrict__ blob,
    const float* __restrict__ scale, float* __restrict__ out, int nAtoms)
{
    __shared__ __align__(16) unsigned short xs[64 * 256];  // swizzled: idx ^= (row&7)<<3

    const int tid = threadIdx.x;
    const int lane = tid & 63;
    const int w = tid >> 6;          // 0..7
    const int l15 = lane & 15;
    const int g = lane >> 4;
    const long long blockRow = (long long)blockIdx.x * 64;

    {
        const char* gsrc = (const char*)(x2b + (size_t)blockIdx.x * 16384) + (size_t)tid * 16;
        char* lbase = (char*)xs + w * 1024;   // wave-uniform
#pragma unroll
        for (int i = 0; i < 4; ++i) {
            __builtin_amdgcn_global_load_lds(
                (const __attribute__((address_space(1))) unsigned int*)(gsrc + i * 8192),
                (__attribute__((address_space(3))) unsigned int*)(lbase + i * 8192),
                16, 0, 0);
        }
        asm volatile("s_waitcnt vmcnt(0)" ::: "memory");
    }

    const float sc = scale[0];
    f32x4 acc[4][2];
    float xrun[4][2][4];

    for (int L = 0; L < 7; ++L) {
        __syncthreads();             // L=0: fences the DMA for all waves

#pragma unroll
        for (int mt = 0; mt < 4; ++mt)
#pragma unroll
            for (int ct = 0; ct < 2; ++ct) acc[mt][ct] = (f32x4){0, 0, 0, 0};

        const unsigned short* wlayer = blob + (size_t)L * 65536;

        for (int c = 0; c < 8; ++c) {
            bf16x8 af[4], bfr[2];
#pragma unroll
            for (int mt = 0; mt < 4; ++mt) {
                int arow = mt * 16 + l15;
                int idx = (arow * 256 + c * 32 + g * 8) ^ ((arow & 7) << 3);
                af[mt] = *reinterpret_cast<const bf16x8*>(&xs[idx]);
            }
#pragma unroll
            for (int ct = 0; ct < 2; ++ct) {
                int n = w * 32 + ct * 16 + l15;
                bfr[ct] = *reinterpret_cast<const bf16x8*>(wlayer + ((size_t)c * 1024 + g * 256 + n) * 8);
            }
#pragma unroll
            for (int mt = 0; mt < 4; ++mt)
#pragma unroll
                for (int ct = 0; ct < 2; ++ct)
                    acc[mt][ct] = __builtin_amdgcn_mfma_f32_16x16x32_bf16(
                        af[mt], bfr[ct], acc[mt][ct], 0, 0, 0);
        }

        __syncthreads();

        if (L == 0) {
#pragma unroll
            for (int mt = 0; mt < 4; ++mt)
#pragma unroll
                for (int ct = 0; ct < 2; ++ct)
#pragma unroll
                    for (int r = 0; r < 4; ++r)
                        xrun[mt][ct][r] = ssilu(acc[mt][ct][r] * sc);
        } else if (L == 1 || L == 3 || L == 5) {
#pragma unroll
            for (int mt = 0; mt < 4; ++mt)
#pragma unroll
                for (int ct = 0; ct < 2; ++ct)
#pragma unroll
                    for (int r = 0; r < 4; ++r) {
                        float v = ssilu(acc[mt][ct][r]);
                        int row = mt * 16 + g * 4 + r;
                        int col = w * 32 + ct * 16 + l15;
                        xs[(row * 256 + col) ^ ((row & 7) << 3)] = f2bf(v);
                    }
            continue;
        } else {
#pragma unroll
            for (int mt = 0; mt < 4; ++mt)
#pragma unroll
                for (int ct = 0; ct < 2; ++ct)
#pragma unroll
                    for (int r = 0; r < 4; ++r)
                        xrun[mt][ct][r] = (xrun[mt][ct][r] + ssilu(acc[mt][ct][r])) * INV_SQRT2f;
        }

        if (L < 6) {
#pragma unroll
            for (int mt = 0; mt < 4; ++mt)
#pragma unroll
                for (int ct = 0; ct < 2; ++ct)
#pragma unroll
                    for (int r = 0; r < 4; ++r) {
                        int row = mt * 16 + g * 4 + r;
                        int col = w * 32 + ct * 16 + l15;
                        xs[(row * 256 + col) ^ ((row & 7) << 3)] = f2bf(xrun[mt][ct][r]);
                    }
        } else {
#pragma unroll
            for (int mt = 0; mt < 4; ++mt) {
#pragma unroll
                for (int r = 0; r < 4; ++r) {
                    long long grow = blockRow + mt * 16 + g * 4 + r;
                    if (grow < nAtoms) {
#pragma unroll
                        for (int ct = 0; ct < 2; ++ct)
                            out[grow * 256 + w * 32 + ct * 16 + l15] = xrun[mt][ct][r];
                    }
                }
            }
        }
    }
}

// ---------------------------------------------------------------------------
extern "C" void kernel_launch(void* const* d_in, const int* in_sizes, int n_in,
                              void* d_out, int out_size, void* d_ws, size_t ws_size,
                              hipStream_t stream)
{
    const float* m     = (const float*)d_in[1];
    const float* rbf   = (const float*)d_in[2];
    const int*   id_j  = (const int*)d_in[3];
    const float* W_rbf = (const float*)d_in[4];
    const float* W1    = (const float*)d_in[5];
    const float* res_W = (const float*)d_in[6];
    const float* scale = (const float*)d_in[7];

    const int nAtoms = in_sizes[0] / 256;   // 50000
    const int nEdges = in_sizes[1] / 256;   // 1000000

    float* out = (float*)d_out;

    const int nTiles = (nAtoms + 63) / 64;  // 782

    // ws layout (bytes):
    //   [0, 25624576)            x2b: bf16 swizzled tiles [782][64*256]
    //   [25690112, 26607616)     blob: bf16 7*65536
    //   [26738688, ...)          int scratch
    unsigned short* x2b  = (unsigned short*)d_ws;
    unsigned short* blob = (unsigned short*)((char*)d_ws + 25690112);
    int* ibase   = (int*)((char*)d_ws + 26738688);
    int* counts  = ibase;                 // 65536
    int* offsets = ibase + 65536;         // 65536
    int* cursor  = ibase + 131072;        // 65536
    int* bsum    = ibase + 196608;        // 1024
    int* order   = ibase + 197632;        // nEdges

    zero_kernel<<<64, 256, 0, stream>>>(counts, 65536);

    wconv_kernel<<<56, 256, 0, stream>>>(W1, res_W, blob);

    hist_kernel<<<2048, 256, 0, stream>>>(id_j, counts, nEdges);
    int nb = (nAtoms + 1023) / 1024;
    scan_reduce<<<nb, 256, 0, stream>>>(counts, bsum, nAtoms);
    scan_sums<<<1, 64, 0, stream>>>(bsum, nb);
    scan_write<<<nb, 256, 0, stream>>>(counts, bsum, offsets, cursor, nAtoms);
    order_kernel<<<2048, 256, 0, stream>>>(id_j, cursor, order, nEdges);

    gather_kernel<<<(nAtoms + 7) / 8, 256, 0, stream>>>(m, rbf, order, offsets,
                                                        counts, W_rbf, x2b);

    dense_kernel<<<nTiles, 512, 0, stream>>>(x2b, blob, scale, out, nAtoms);
}

// Round 6
// 523.956 us; speedup vs baseline: 1.4063x; 1.4063x over previous
//
#include <hip/hip_runtime.h>
#include <math.h>

#define INV_SQRT2f 0.70710678118654752440f
#define SILU_SCALEf (1.0f / 0.6f)

typedef __attribute__((ext_vector_type(8))) short bf16x8;
typedef __attribute__((ext_vector_type(4))) short bf16x4;
typedef __attribute__((ext_vector_type(4))) float f32x4;

__device__ __forceinline__ float ssilu(float v) {
    return (v / (1.0f + __expf(-v))) * SILU_SCALEf;
}

__device__ __forceinline__ unsigned short f2bf(float f) {
    unsigned int u = __float_as_uint(f);
    unsigned int r = (u + 0x7FFFu + ((u >> 16) & 1u)) >> 16;
    return (unsigned short)r;
}

// ---------------------------------------------------------------------------
// Edge phase: counting-sort by atom (CSR) — unchanged (measured-good).
// ---------------------------------------------------------------------------
__global__ void zero_kernel(int* __restrict__ p, int n)
{
    int i = blockIdx.x * blockDim.x + threadIdx.x;
    for (; i < n; i += gridDim.x * blockDim.x) p[i] = 0;
}

__global__ void hist_kernel(const int* __restrict__ id_j, int* __restrict__ counts,
                            int nEdges)
{
    int i = blockIdx.x * blockDim.x + threadIdx.x;
    for (; i < nEdges; i += gridDim.x * blockDim.x)
        atomicAdd(&counts[id_j[i]], 1);
}

__global__ void scan_reduce(const int* __restrict__ counts, int* __restrict__ bsum,
                            int n)
{
    __shared__ int s[256];
    int base = blockIdx.x * 1024;
    int t = threadIdx.x;
    int v = 0;
#pragma unroll
    for (int k = 0; k < 4; ++k) {
        int i = base + t + k * 256;
        if (i < n) v += counts[i];
    }
    s[t] = v;
    __syncthreads();
    for (int off = 128; off > 0; off >>= 1) {
        if (t < off) s[t] += s[t + off];
        __syncthreads();
    }
    if (t == 0) bsum[blockIdx.x] = s[0];
}

// wave-parallel exclusive scan of chunk totals (single 64-thread block)
__global__ void scan_sums(int* __restrict__ bsum, int nb)
{
    int l = threadIdx.x & 63;
    int carry = 0;
    for (int base = 0; base < nb; base += 64) {
        int idx = base + l;
        int orig = (idx < nb) ? bsum[idx] : 0;
        int v = orig;
#pragma unroll
        for (int off = 1; off < 64; off <<= 1) {
            int u = __shfl_up(v, off, 64);
            if (l >= off) v += u;
        }
        if (idx < nb) bsum[idx] = carry + v - orig;
        carry += __shfl(v, 63, 64);
    }
}

__global__ void scan_write(const int* __restrict__ counts, const int* __restrict__ bsum,
                           int* __restrict__ offsets, int* __restrict__ cursor, int n)
{
    __shared__ int s[256];
    int base = blockIdx.x * 1024;
    int t = threadIdx.x;
    int v[4];
    int tot = 0;
#pragma unroll
    for (int k = 0; k < 4; ++k) {
        int i = base + t * 4 + k;
        int c = (i < n) ? counts[i] : 0;
        v[k] = tot; tot += c;
    }
    s[t] = tot;
    __syncthreads();
    for (int off = 1; off < 256; off <<= 1) {
        int x = (t >= off) ? s[t - off] : 0;
        __syncthreads();
        s[t] += x;
        __syncthreads();
    }
    int excl = (t > 0) ? s[t - 1] : 0;
    int bo = bsum[blockIdx.x];
#pragma unroll
    for (int k = 0; k < 4; ++k) {
        int i = base + t * 4 + k;
        if (i < n) { int o = bo + excl + v[k]; offsets[i] = o; cursor[i] = o; }
    }
}

__global__ void order_kernel(const int* __restrict__ id_j, int* __restrict__ cursor,
                             int* __restrict__ order, int nEdges)
{
    int i = blockIdx.x * blockDim.x + threadIdx.x;
    for (; i < nEdges; i += gridDim.x * blockDim.x) {
        int j = id_j[i];
        int p = atomicAdd(&cursor[j], 1);
        order[p] = i;
    }
}

// ---------------------------------------------------------------------------
// Weight conversion: f32 [256][256] row-major -> bf16 fragment-ordered blob.
// ---------------------------------------------------------------------------
__global__ void __launch_bounds__(256) wconv_kernel(
    const float* __restrict__ W1, const float* __restrict__ res_W,
    unsigned short* __restrict__ blob)
{
    __shared__ float ws[32][260];
    const int b = blockIdx.x;        // b = L*8 + c
    const int L = b >> 3, c = b & 7;
    const int t = threadIdx.x;
    const float* W = (L == 0) ? W1 : res_W + (size_t)(L - 1) * 65536;

#pragma unroll
    for (int r = 0; r < 32; ++r)
        ws[r][t] = W[(size_t)(c * 32 + r) * 256 + t];
    __syncthreads();

    unsigned short* dst = blob + (size_t)b * 8192;
#pragma unroll
    for (int q = 0; q < 32; ++q) {
        int flat = q * 256 + t;
        int jj = flat & 7, n = (flat >> 3) & 255, g = flat >> 11;
        dst[flat] = f2bf(ws[g * 8 + jj][n]);
    }
}

// ---------------------------------------------------------------------------
// Gather v6: 1 wave per atom, thread owns 4 columns.
// Rationale (R4/R5 post-mortem): per-edge LDS broadcast reads were replayed by
// all 4 waves of the old 256-thread block -> ~4x LDS-pipe serialization per CU;
// R5 showed in-flight bytes alone don't fix it (occupancy collapsed). Here ONE
// wave issues {1 ds_read_b128 (m, distributed) + 4 ds_read_b128 (rbf broadcast)}
// per edge, no barriers (wave-synchronous), and staging is double-buffered
// 8-edge chunks of global_load_lds with counted s_waitcnt vmcnt(10) so the
// next chunk's 10 DMAs stay in flight during consume. 18 KB LDS -> 8 blocks/CU
// -> ~80-160 KB outstanding per CU (>> ~20 KB BW-delay product).
// ---------------------------------------------------------------------------
__global__ void __launch_bounds__(64, 2) gather_kernel(
    const float* __restrict__ m, const float* __restrict__ rbf,
    const int* __restrict__ order, const int* __restrict__ offsets,
    const int* __restrict__ counts, const float* __restrict__ W_rbf,
    unsigned short* __restrict__ x2b)
{
    __shared__ __align__(16) float mbuf[2][8][256];   // 16 KB
    __shared__ __align__(16) float rbuf[2][8][16];    // 1 KB
    __shared__ int ord_lds[256];                      // 1 KB

    const int lane = threadIdx.x;    // 0..63
    const int j = blockIdx.x;

    // thread's 4 columns of W_rbf: w4[k] = W_rbf[k][4*lane .. 4*lane+3]
    f32x4 w4[16];
#pragma unroll
    for (int k = 0; k < 16; ++k)
        w4[k] = *reinterpret_cast<const f32x4*>(W_rbf + k * 256 + 4 * lane);

    const int s = offsets[j];
    const int n = counts[j];
    f32x4 acc = (f32x4){0.0f, 0.0f, 0.0f, 0.0f};

#define STAGE(c_) do {                                                          \
    const int cs_ = (c_) * 8;                                                   \
    const int bs_ = (c_) & 1;                                                   \
    _Pragma("unroll")                                                           \
    for (int q_ = 0; q_ < 8; ++q_) {                                            \
        int rp_ = cs_ + q_; if (rp_ > nn - 1) rp_ = nn - 1;                     \
        int e_ = ord_lds[rp_];                                                  \
        const float* src_ = m + (size_t)e_ * 256 + lane * 4;                    \
        __builtin_amdgcn_global_load_lds(                                       \
            (const __attribute__((address_space(1))) unsigned int*)src_,        \
            (__attribute__((address_space(3))) unsigned int*)&mbuf[bs_][q_][0], \
            16, 0, 0);                                                          \
    }                                                                           \
    {                                                                           \
        int rp_ = cs_ + (lane >> 4); if (rp_ > nn - 1) rp_ = nn - 1;            \
        int e_ = ord_lds[rp_];                                                  \
        const float* src_ = rbf + (size_t)e_ * 16 + (lane & 15);                \
        __builtin_amdgcn_global_load_lds(                                       \
            (const __attribute__((address_space(1))) unsigned int*)src_,        \
            (__attribute__((address_space(3))) unsigned int*)&rbuf[bs_][0][0],  \
            4, 0, 0);                                                           \
        rp_ = cs_ + 4 + (lane >> 4); if (rp_ > nn - 1) rp_ = nn - 1;            \
        e_ = ord_lds[rp_];                                                      \
        src_ = rbf + (size_t)e_ * 16 + (lane & 15);                             \
        __builtin_amdgcn_global_load_lds(                                       \
            (const __attribute__((address_space(1))) unsigned int*)src_,        \
            (__attribute__((address_space(3))) unsigned int*)&rbuf[bs_][4][0],  \
            4, 0, 0);                                                           \
    }                                                                           \
} while (0)

#define CONSUME(b_, i_) do {                                                    \
    f32x4 mv = *reinterpret_cast<const f32x4*>(&mbuf[b_][i_][4 * lane]);        \
    const f32x4* rr = reinterpret_cast<const f32x4*>(&rbuf[b_][i_][0]);         \
    f32x4 r0 = rr[0], r1 = rr[1], r2 = rr[2], r3 = rr[3];                       \
    f32x4 gg = w4[0]*r0[0] + w4[1]*r0[1] + w4[2]*r0[2] + w4[3]*r0[3]            \
             + w4[4]*r1[0] + w4[5]*r1[1] + w4[6]*r1[2] + w4[7]*r1[3]            \
             + w4[8]*r2[0] + w4[9]*r2[1] + w4[10]*r2[2] + w4[11]*r2[3]          \
             + w4[12]*r3[0] + w4[13]*r3[1] + w4[14]*r3[2] + w4[15]*r3[3];       \
    acc += mv * gg;                                                             \
} while (0)

    for (int base = 0; base < n; base += 256) {
        const int nn = (n - base < 256) ? (n - base) : 256;

        // stage this super-round's edge ids into LDS (single wave: no barrier;
        // compiler orders the global->ds_write->ds_read chain via waitcnts)
#pragma unroll
        for (int u = 0; u < 4; ++u) {
            int idx = lane + u * 64;
            int cl = (idx < nn) ? idx : (nn - 1);
            ord_lds[idx] = order[s + base + cl];
        }

        const int K = (nn + 7) >> 3;

        STAGE(0);
        for (int k = 0; k < K; ++k) {
            if (k + 1 < K) {
                STAGE(k + 1);
                asm volatile("s_waitcnt vmcnt(10)" ::: "memory");
            } else {
                asm volatile("s_waitcnt vmcnt(0)" ::: "memory");
            }
            const int cnt = (nn - k * 8 < 8) ? (nn - k * 8) : 8;
            if (cnt == 8) {
                if (k & 1) {
#pragma unroll
                    for (int i = 0; i < 8; ++i) CONSUME(1, i);
                } else {
#pragma unroll
                    for (int i = 0; i < 8; ++i) CONSUME(0, i);
                }
            } else {
                if (k & 1) {
                    for (int i = 0; i < cnt; ++i) CONSUME(1, i);
                } else {
                    for (int i = 0; i < cnt; ++i) CONSUME(0, i);
                }
            }
        }
    }
#undef STAGE
#undef CONSUME

    // store: bf16 in the dense kernel's swizzled LDS image layout
    const int tile = j >> 6, r = j & 63;
    const int idx = (r * 256 + 4 * lane) ^ ((r & 7) << 3);
    bf16x4 o = {(short)f2bf(acc[0]), (short)f2bf(acc[1]),
                (short)f2bf(acc[2]), (short)f2bf(acc[3])};
    *reinterpret_cast<bf16x4*>(x2b + (size_t)tile * 16384 + idx) = o;
}

// ---------------------------------------------------------------------------
// Dense chain, 8-wave variant (measured-good). Pure global->LDS DMA load of
// the pre-swizzled bf16 x2b image, then 7-layer MFMA chain.
// ---------------------------------------------------------------------------
__global__ void __launch_bounds__(512) dense_kernel(
    const unsigned short* __restrict__ x2b, const unsigned short* __restrict__ blob,
    const float* __restrict__ scale, float* __restrict__ out, int nAtoms)
{
    __shared__ __align__(16) unsigned short xs[64 * 256];  // swizzled: idx ^= (row&7)<<3

    const int tid = threadIdx.x;
    const int lane = tid & 63;
    const int w = tid >> 6;          // 0..7
    const int l15 = lane & 15;
    const int g = lane >> 4;
    const long long blockRow = (long long)blockIdx.x * 64;

    {
        const char* gsrc = (const char*)(x2b + (size_t)blockIdx.x * 16384) + (size_t)tid * 16;
        char* lbase = (char*)xs + w * 1024;   // wave-uniform
#pragma unroll
        for (int i = 0; i < 4; ++i) {
            __builtin_amdgcn_global_load_lds(
                (const __attribute__((address_space(1))) unsigned int*)(gsrc + i * 8192),
                (__attribute__((address_space(3))) unsigned int*)(lbase + i * 8192),
                16, 0, 0);
        }
        asm volatile("s_waitcnt vmcnt(0)" ::: "memory");
    }

    const float sc = scale[0];
    f32x4 acc[4][2];
    float xrun[4][2][4];

    for (int L = 0; L < 7; ++L) {
        __syncthreads();             // L=0: fences the DMA for all waves

#pragma unroll
        for (int mt = 0; mt < 4; ++mt)
#pragma unroll
            for (int ct = 0; ct < 2; ++ct) acc[mt][ct] = (f32x4){0, 0, 0, 0};

        const unsigned short* wlayer = blob + (size_t)L * 65536;

        for (int c = 0; c < 8; ++c) {
            bf16x8 af[4], bfr[2];
#pragma unroll
            for (int mt = 0; mt < 4; ++mt) {
                int arow = mt * 16 + l15;
                int idx = (arow * 256 + c * 32 + g * 8) ^ ((arow & 7) << 3);
                af[mt] = *reinterpret_cast<const bf16x8*>(&xs[idx]);
            }
#pragma unroll
            for (int ct = 0; ct < 2; ++ct) {
                int n = w * 32 + ct * 16 + l15;
                bfr[ct] = *reinterpret_cast<const bf16x8*>(wlayer + ((size_t)c * 1024 + g * 256 + n) * 8);
            }
#pragma unroll
            for (int mt = 0; mt < 4; ++mt)
#pragma unroll
                for (int ct = 0; ct < 2; ++ct)
                    acc[mt][ct] = __builtin_amdgcn_mfma_f32_16x16x32_bf16(
                        af[mt], bfr[ct], acc[mt][ct], 0, 0, 0);
        }

        __syncthreads();

        if (L == 0) {
#pragma unroll
            for (int mt = 0; mt < 4; ++mt)
#pragma unroll
                for (int ct = 0; ct < 2; ++ct)
#pragma unroll
                    for (int r = 0; r < 4; ++r)
                        xrun[mt][ct][r] = ssilu(acc[mt][ct][r] * sc);
        } else if (L == 1 || L == 3 || L == 5) {
#pragma unroll
            for (int mt = 0; mt < 4; ++mt)
#pragma unroll
                for (int ct = 0; ct < 2; ++ct)
#pragma unroll
                    for (int r = 0; r < 4; ++r) {
                        float v = ssilu(acc[mt][ct][r]);
                        int row = mt * 16 + g * 4 + r;
                        int col = w * 32 + ct * 16 + l15;
                        xs[(row * 256 + col) ^ ((row & 7) << 3)] = f2bf(v);
                    }
            continue;
        } else {
#pragma unroll
            for (int mt = 0; mt < 4; ++mt)
#pragma unroll
                for (int ct = 0; ct < 2; ++ct)
#pragma unroll
                    for (int r = 0; r < 4; ++r)
                        xrun[mt][ct][r] = (xrun[mt][ct][r] + ssilu(acc[mt][ct][r])) * INV_SQRT2f;
        }

        if (L < 6) {
#pragma unroll
            for (int mt = 0; mt < 4; ++mt)
#pragma unroll
                for (int ct = 0; ct < 2; ++ct)
#pragma unroll
                    for (int r = 0; r < 4; ++r) {
                        int row = mt * 16 + g * 4 + r;
                        int col = w * 32 + ct * 16 + l15;
                        xs[(row * 256 + col) ^ ((row & 7) << 3)] = f2bf(xrun[mt][ct][r]);
                    }
        } else {
#pragma unroll
            for (int mt = 0; mt < 4; ++mt) {
#pragma unroll
                for (int r = 0; r < 4; ++r) {
                    long long grow = blockRow + mt * 16 + g * 4 + r;
                    if (grow < nAtoms) {
#pragma unroll
                        for (int ct = 0; ct < 2; ++ct)
                            out[grow * 256 + w * 32 + ct * 16 + l15] = xrun[mt][ct][r];
                    }
                }
            }
        }
    }
}

// ---------------------------------------------------------------------------
extern "C" void kernel_launch(void* const* d_in, const int* in_sizes, int n_in,
                              void* d_out, int out_size, void* d_ws, size_t ws_size,
                              hipStream_t stream)
{
    const float* m     = (const float*)d_in[1];
    const float* rbf   = (const float*)d_in[2];
    const int*   id_j  = (const int*)d_in[3];
    const float* W_rbf = (const float*)d_in[4];
    const float* W1    = (const float*)d_in[5];
    const float* res_W = (const float*)d_in[6];
    const float* scale = (const float*)d_in[7];

    const int nAtoms = in_sizes[0] / 256;   // 50000
    const int nEdges = in_sizes[1] / 256;   // 1000000

    float* out = (float*)d_out;

    const int nTiles = (nAtoms + 63) / 64;  // 782

    // ws layout (bytes):
    //   [0, 25624576)            x2b: bf16 swizzled tiles [782][64*256]
    //   [25690112, 26607616)     blob: bf16 7*65536
    //   [26738688, ...)          int scratch
    unsigned short* x2b  = (unsigned short*)d_ws;
    unsigned short* blob = (unsigned short*)((char*)d_ws + 25690112);
    int* ibase   = (int*)((char*)d_ws + 26738688);
    int* counts  = ibase;                 // 65536
    int* offsets = ibase + 65536;         // 65536
    int* cursor  = ibase + 131072;        // 65536
    int* bsum    = ibase + 196608;        // 1024
    int* order   = ibase + 197632;        // nEdges

    zero_kernel<<<64, 256, 0, stream>>>(counts, 65536);

    wconv_kernel<<<56, 256, 0, stream>>>(W1, res_W, blob);

    hist_kernel<<<2048, 256, 0, stream>>>(id_j, counts, nEdges);
    int nb = (nAtoms + 1023) / 1024;
    scan_reduce<<<nb, 256, 0, stream>>>(counts, bsum, nAtoms);
    scan_sums<<<1, 64, 0, stream>>>(bsum, nb);
    scan_write<<<nb, 256, 0, stream>>>(counts, bsum, offsets, cursor, nAtoms);
    order_kernel<<<2048, 256, 0, stream>>>(id_j, cursor, order, nEdges);

    gather_kernel<<<nAtoms, 64, 0, stream>>>(m, rbf, order, offsets, counts,
                                             W_rbf, x2b);

    dense_kernel<<<nTiles, 512, 0, stream>>>(x2b, blob, scale, out, nAtoms);
}

// Round 7
// 509.447 us; speedup vs baseline: 1.4463x; 1.0285x over previous
//
#include <hip/hip_runtime.h>
#include <hip/hip_fp16.h>
#include <math.h>

#define INV_SQRT2f 0.70710678118654752440f
#define SILU_SCALEf (1.0f / 0.6f)

typedef __attribute__((ext_vector_type(8))) short bf16x8;
typedef __attribute__((ext_vector_type(4))) short bf16x4;
typedef __attribute__((ext_vector_type(4))) float f32x4;

__device__ __forceinline__ float ssilu(float v) {
    return (v / (1.0f + __expf(-v))) * SILU_SCALEf;
}

__device__ __forceinline__ unsigned short f2bf(float f) {
    unsigned int u = __float_as_uint(f);
    unsigned int r = (u + 0x7FFFu + ((u >> 16) & 1u)) >> 16;
    return (unsigned short)r;
}

// ---------------------------------------------------------------------------
// Edge phase: counting-sort by atom (CSR) — unchanged (measured-good).
// ---------------------------------------------------------------------------
__global__ void zero_kernel(int* __restrict__ p, int n)
{
    int i = blockIdx.x * blockDim.x + threadIdx.x;
    for (; i < n; i += gridDim.x * blockDim.x) p[i] = 0;
}

__global__ void hist_kernel(const int* __restrict__ id_j, int* __restrict__ counts,
                            int nEdges)
{
    int i = blockIdx.x * blockDim.x + threadIdx.x;
    for (; i < nEdges; i += gridDim.x * blockDim.x)
        atomicAdd(&counts[id_j[i]], 1);
}

__global__ void scan_reduce(const int* __restrict__ counts, int* __restrict__ bsum,
                            int n)
{
    __shared__ int s[256];
    int base = blockIdx.x * 1024;
    int t = threadIdx.x;
    int v = 0;
#pragma unroll
    for (int k = 0; k < 4; ++k) {
        int i = base + t + k * 256;
        if (i < n) v += counts[i];
    }
    s[t] = v;
    __syncthreads();
    for (int off = 128; off > 0; off >>= 1) {
        if (t < off) s[t] += s[t + off];
        __syncthreads();
    }
    if (t == 0) bsum[blockIdx.x] = s[0];
}

// wave-parallel exclusive scan of chunk totals (single 64-thread block)
__global__ void scan_sums(int* __restrict__ bsum, int nb)
{
    int l = threadIdx.x & 63;
    int carry = 0;
    for (int base = 0; base < nb; base += 64) {
        int idx = base + l;
        int orig = (idx < nb) ? bsum[idx] : 0;
        int v = orig;
#pragma unroll
        for (int off = 1; off < 64; off <<= 1) {
            int u = __shfl_up(v, off, 64);
            if (l >= off) v += u;
        }
        if (idx < nb) bsum[idx] = carry + v - orig;
        carry += __shfl(v, 63, 64);
    }
}

__global__ void scan_write(const int* __restrict__ counts, const int* __restrict__ bsum,
                           int* __restrict__ offsets, int* __restrict__ cursor, int n)
{
    __shared__ int s[256];
    int base = blockIdx.x * 1024;
    int t = threadIdx.x;
    int v[4];
    int tot = 0;
#pragma unroll
    for (int k = 0; k < 4; ++k) {
        int i = base + t * 4 + k;
        int c = (i < n) ? counts[i] : 0;
        v[k] = tot; tot += c;
    }
    s[t] = tot;
    __syncthreads();
    for (int off = 1; off < 256; off <<= 1) {
        int x = (t >= off) ? s[t - off] : 0;
        __syncthreads();
        s[t] += x;
        __syncthreads();
    }
    int excl = (t > 0) ? s[t - 1] : 0;
    int bo = bsum[blockIdx.x];
#pragma unroll
    for (int k = 0; k < 4; ++k) {
        int i = base + t * 4 + k;
        if (i < n) { int o = bo + excl + v[k]; offsets[i] = o; cursor[i] = o; }
    }
}

// order_kernel now ALSO scatters each edge's rbf row (f16, 32 B) into CSR
// order. This converts the gather's 1M random 64-B rbf reads (1M random
// 128-B line-fetches against the per-CU miss budget) into a contiguous
// streaming read. rbf read here is fully coalesced (thread i reads 64 B at
// i*64); the 32-B scatter writes are fire-and-forget.
__global__ void order_kernel(const int* __restrict__ id_j, int* __restrict__ cursor,
                             int* __restrict__ order, const float* __restrict__ rbf,
                             __half* __restrict__ rbf_h, int nEdges)
{
    int i = blockIdx.x * blockDim.x + threadIdx.x;
    for (; i < nEdges; i += gridDim.x * blockDim.x) {
        int j = id_j[i];
        int p = atomicAdd(&cursor[j], 1);
        order[p] = i;
        const float4* rs = reinterpret_cast<const float4*>(rbf + (size_t)i * 16);
        float4 q0 = rs[0], q1 = rs[1], q2 = rs[2], q3 = rs[3];
        __half2 h[8];
        h[0] = __float22half2_rn(make_float2(q0.x, q0.y));
        h[1] = __float22half2_rn(make_float2(q0.z, q0.w));
        h[2] = __float22half2_rn(make_float2(q1.x, q1.y));
        h[3] = __float22half2_rn(make_float2(q1.z, q1.w));
        h[4] = __float22half2_rn(make_float2(q2.x, q2.y));
        h[5] = __float22half2_rn(make_float2(q2.z, q2.w));
        h[6] = __float22half2_rn(make_float2(q3.x, q3.y));
        h[7] = __float22half2_rn(make_float2(q3.z, q3.w));
        uint4* dst = reinterpret_cast<uint4*>(rbf_h + (size_t)p * 16);
        dst[0] = *reinterpret_cast<const uint4*>(&h[0]);
        dst[1] = *reinterpret_cast<const uint4*>(&h[4]);
    }
}

// ---------------------------------------------------------------------------
// Weight conversion: f32 [256][256] row-major -> bf16 fragment-ordered blob.
// ---------------------------------------------------------------------------
__global__ void __launch_bounds__(256) wconv_kernel(
    const float* __restrict__ W1, const float* __restrict__ res_W,
    unsigned short* __restrict__ blob)
{
    __shared__ float ws[32][260];
    const int b = blockIdx.x;        // b = L*8 + c
    const int L = b >> 3, c = b & 7;
    const int t = threadIdx.x;
    const float* W = (L == 0) ? W1 : res_W + (size_t)(L - 1) * 65536;

#pragma unroll
    for (int r = 0; r < 32; ++r)
        ws[r][t] = W[(size_t)(c * 32 + r) * 256 + t];
    __syncthreads();

    unsigned short* dst = blob + (size_t)b * 8192;
#pragma unroll
    for (int q = 0; q < 32; ++q) {
        int flat = q * 256 + t;
        int jj = flat & 7, n = (flat >> 3) & 255, g = flat >> 11;
        dst[flat] = f2bf(ws[g * 8 + jj][n]);
    }
}

// ---------------------------------------------------------------------------
// Gather v7: R6's 1-wave-per-atom counted-vmcnt DMA pipeline, with rbf now
// staged from the CSR-sorted f16 copy (contiguous 256 B per 8-edge chunk,
// ONE width-4 DMA) instead of 2 random DMAs. 9 DMAs/chunk -> vmcnt(9).
// m staging, consume layout, and store unchanged (measured-good).
// ---------------------------------------------------------------------------
__global__ void __launch_bounds__(64, 2) gather_kernel(
    const float* __restrict__ m, const __half* __restrict__ rbf_h,
    const int* __restrict__ order, const int* __restrict__ offsets,
    const int* __restrict__ counts, const float* __restrict__ W_rbf,
    unsigned short* __restrict__ x2b)
{
    __shared__ __align__(16) float mbuf[2][8][256];   // 16 KB
    __shared__ __align__(16) __half rbuf[2][8][16];   // 0.5 KB
    __shared__ int ord_lds[256];                      // 1 KB

    const int lane = threadIdx.x;    // 0..63
    const int j = blockIdx.x;

    // thread's 4 columns of W_rbf: w4[k] = W_rbf[k][4*lane .. 4*lane+3]
    f32x4 w4[16];
#pragma unroll
    for (int k = 0; k < 16; ++k)
        w4[k] = *reinterpret_cast<const f32x4*>(W_rbf + k * 256 + 4 * lane);

    const int s = offsets[j];
    const int n = counts[j];
    f32x4 acc = (f32x4){0.0f, 0.0f, 0.0f, 0.0f};

#define STAGE(c_) do {                                                          \
    const int cs_ = (c_) * 8;                                                   \
    const int bs_ = (c_) & 1;                                                   \
    _Pragma("unroll")                                                           \
    for (int q_ = 0; q_ < 8; ++q_) {                                            \
        int rp_ = cs_ + q_; if (rp_ > nn - 1) rp_ = nn - 1;                     \
        int e_ = ord_lds[rp_];                                                  \
        const float* src_ = m + (size_t)e_ * 256 + lane * 4;                    \
        __builtin_amdgcn_global_load_lds(                                       \
            (const __attribute__((address_space(1))) unsigned int*)src_,        \
            (__attribute__((address_space(3))) unsigned int*)&mbuf[bs_][q_][0], \
            16, 0, 0);                                                          \
    }                                                                           \
    {                                                                           \
        const __half* src_ = rbf_h + (size_t)(gb + cs_) * 16 + lane * 2;        \
        __builtin_amdgcn_global_load_lds(                                       \
            (const __attribute__((address_space(1))) unsigned int*)src_,        \
            (__attribute__((address_space(3))) unsigned int*)&rbuf[bs_][0][0],  \
            4, 0, 0);                                                           \
    }                                                                           \
} while (0)

#define CONSUME(b_, i_) do {                                                    \
    f32x4 mv = *reinterpret_cast<const f32x4*>(&mbuf[b_][i_][4 * lane]);        \
    const __half2* rh = reinterpret_cast<const __half2*>(&rbuf[b_][i_][0]);     \
    float2 p0 = __half22float2(rh[0]); float2 p1 = __half22float2(rh[1]);       \
    float2 p2 = __half22float2(rh[2]); float2 p3 = __half22float2(rh[3]);       \
    float2 p4 = __half22float2(rh[4]); float2 p5 = __half22float2(rh[5]);       \
    float2 p6 = __half22float2(rh[6]); float2 p7 = __half22float2(rh[7]);       \
    f32x4 gg = w4[0]*p0.x + w4[1]*p0.y + w4[2]*p1.x + w4[3]*p1.y                \
             + w4[4]*p2.x + w4[5]*p2.y + w4[6]*p3.x + w4[7]*p3.y                \
             + w4[8]*p4.x + w4[9]*p4.y + w4[10]*p5.x + w4[11]*p5.y              \
             + w4[12]*p6.x + w4[13]*p6.y + w4[14]*p7.x + w4[15]*p7.y;           \
    acc += mv * gg;                                                             \
} while (0)

    for (int base = 0; base < n; base += 256) {
        const int nn = (n - base < 256) ? (n - base) : 256;
        const int gb = s + base;     // absolute CSR position of this super-round

        // stage this super-round's edge ids into LDS (single wave: no barrier)
#pragma unroll
        for (int u = 0; u < 4; ++u) {
            int idx = lane + u * 64;
            int cl = (idx < nn) ? idx : (nn - 1);
            ord_lds[idx] = order[gb + cl];
        }

        const int K = (nn + 7) >> 3;

        STAGE(0);
        for (int k = 0; k < K; ++k) {
            if (k + 1 < K) {
                STAGE(k + 1);
                asm volatile("s_waitcnt vmcnt(9)" ::: "memory");
            } else {
                asm volatile("s_waitcnt vmcnt(0)" ::: "memory");
            }
            const int cnt = (nn - k * 8 < 8) ? (nn - k * 8) : 8;
            if (cnt == 8) {
                if (k & 1) {
#pragma unroll
                    for (int i = 0; i < 8; ++i) CONSUME(1, i);
                } else {
#pragma unroll
                    for (int i = 0; i < 8; ++i) CONSUME(0, i);
                }
            } else {
                if (k & 1) {
                    for (int i = 0; i < cnt; ++i) CONSUME(1, i);
                } else {
                    for (int i = 0; i < cnt; ++i) CONSUME(0, i);
                }
            }
        }
    }
#undef STAGE
#undef CONSUME

    // store: bf16 in the dense kernel's swizzled LDS image layout
    const int tile = j >> 6, r = j & 63;
    const int idx = (r * 256 + 4 * lane) ^ ((r & 7) << 3);
    bf16x4 o = {(short)f2bf(acc[0]), (short)f2bf(acc[1]),
                (short)f2bf(acc[2]), (short)f2bf(acc[3])};
    *reinterpret_cast<bf16x4*>(x2b + (size_t)tile * 16384 + idx) = o;
}

// ---------------------------------------------------------------------------
// Dense chain, 8-wave variant (measured-good). Pure global->LDS DMA load of
// the pre-swizzled bf16 x2b image, then 7-layer MFMA chain.
// ---------------------------------------------------------------------------
__global__ void __launch_bounds__(512) dense_kernel(
    const unsigned short* __restrict__ x2b, const unsigned short* __restrict__ blob,
    const float* __restrict__ scale, float* __restrict__ out, int nAtoms)
{
    __shared__ __align__(16) unsigned short xs[64 * 256];  // swizzled: idx ^= (row&7)<<3

    const int tid = threadIdx.x;
    const int lane = tid & 63;
    const int w = tid >> 6;          // 0..7
    const int l15 = lane & 15;
    const int g = lane >> 4;
    const long long blockRow = (long long)blockIdx.x * 64;

    {
        const char* gsrc = (const char*)(x2b + (size_t)blockIdx.x * 16384) + (size_t)tid * 16;
        char* lbase = (char*)xs + w * 1024;   // wave-uniform
#pragma unroll
        for (int i = 0; i < 4; ++i) {
            __builtin_amdgcn_global_load_lds(
                (const __attribute__((address_space(1))) unsigned int*)(gsrc + i * 8192),
                (__attribute__((address_space(3))) unsigned int*)(lbase + i * 8192),
                16, 0, 0);
        }
        asm volatile("s_waitcnt vmcnt(0)" ::: "memory");
    }

    const float sc = scale[0];
    f32x4 acc[4][2];
    float xrun[4][2][4];

    for (int L = 0; L < 7; ++L) {
        __syncthreads();             // L=0: fences the DMA for all waves

#pragma unroll
        for (int mt = 0; mt < 4; ++mt)
#pragma unroll
            for (int ct = 0; ct < 2; ++ct) acc[mt][ct] = (f32x4){0, 0, 0, 0};

        const unsigned short* wlayer = blob + (size_t)L * 65536;

        for (int c = 0; c < 8; ++c) {
            bf16x8 af[4], bfr[2];
#pragma unroll
            for (int mt = 0; mt < 4; ++mt) {
                int arow = mt * 16 + l15;
                int idx = (arow * 256 + c * 32 + g * 8) ^ ((arow & 7) << 3);
                af[mt] = *reinterpret_cast<const bf16x8*>(&xs[idx]);
            }
#pragma unroll
            for (int ct = 0; ct < 2; ++ct) {
                int n = w * 32 + ct * 16 + l15;
                bfr[ct] = *reinterpret_cast<const bf16x8*>(wlayer + ((size_t)c * 1024 + g * 256 + n) * 8);
            }
#pragma unroll
            for (int mt = 0; mt < 4; ++mt)
#pragma unroll
                for (int ct = 0; ct < 2; ++ct)
                    acc[mt][ct] = __builtin_amdgcn_mfma_f32_16x16x32_bf16(
                        af[mt], bfr[ct], acc[mt][ct], 0, 0, 0);
        }

        __syncthreads();

        if (L == 0) {
#pragma unroll
            for (int mt = 0; mt < 4; ++mt)
#pragma unroll
                for (int ct = 0; ct < 2; ++ct)
#pragma unroll
                    for (int r = 0; r < 4; ++r)
                        xrun[mt][ct][r] = ssilu(acc[mt][ct][r] * sc);
        } else if (L == 1 || L == 3 || L == 5) {
#pragma unroll
            for (int mt = 0; mt < 4; ++mt)
#pragma unroll
                for (int ct = 0; ct < 2; ++ct)
#pragma unroll
                    for (int r = 0; r < 4; ++r) {
                        float v = ssilu(acc[mt][ct][r]);
                        int row = mt * 16 + g * 4 + r;
                        int col = w * 32 + ct * 16 + l15;
                        xs[(row * 256 + col) ^ ((row & 7) << 3)] = f2bf(v);
                    }
            continue;
        } else {
#pragma unroll
            for (int mt = 0; mt < 4; ++mt)
#pragma unroll
                for (int ct = 0; ct < 2; ++ct)
#pragma unroll
                    for (int r = 0; r < 4; ++r)
                        xrun[mt][ct][r] = (xrun[mt][ct][r] + ssilu(acc[mt][ct][r])) * INV_SQRT2f;
        }

        if (L < 6) {
#pragma unroll
            for (int mt = 0; mt < 4; ++mt)
#pragma unroll
                for (int ct = 0; ct < 2; ++ct)
#pragma unroll
                    for (int r = 0; r < 4; ++r) {
                        int row = mt * 16 + g * 4 + r;
                        int col = w * 32 + ct * 16 + l15;
                        xs[(row * 256 + col) ^ ((row & 7) << 3)] = f2bf(xrun[mt][ct][r]);
                    }
        } else {
#pragma unroll
            for (int mt = 0; mt < 4; ++mt) {
#pragma unroll
                for (int r = 0; r < 4; ++r) {
                    long long grow = blockRow + mt * 16 + g * 4 + r;
                    if (grow < nAtoms) {
#pragma unroll
                        for (int ct = 0; ct < 2; ++ct)
                            out[grow * 256 + w * 32 + ct * 16 + l15] = xrun[mt][ct][r];
                    }
                }
            }
        }
    }
}

// ---------------------------------------------------------------------------
extern "C" void kernel_launch(void* const* d_in, const int* in_sizes, int n_in,
                              void* d_out, int out_size, void* d_ws, size_t ws_size,
                              hipStream_t stream)
{
    const float* m     = (const float*)d_in[1];
    const float* rbf   = (const float*)d_in[2];
    const int*   id_j  = (const int*)d_in[3];
    const float* W_rbf = (const float*)d_in[4];
    const float* W1    = (const float*)d_in[5];
    const float* res_W = (const float*)d_in[6];
    const float* scale = (const float*)d_in[7];

    const int nAtoms = in_sizes[0] / 256;   // 50000
    const int nEdges = in_sizes[1] / 256;   // 1000000

    float* out = (float*)d_out;

    const int nTiles = (nAtoms + 63) / 64;  // 782

    // ws layout (bytes):
    //   [0, 25624576)            x2b: bf16 swizzled tiles [782][64*256]
    //   [25690112, 26607616)     blob: bf16 7*65536
    //   [26738688, 31529216)     int scratch (counts/offsets/cursor/bsum/order)
    //   [31529216, 63530240)     rbf_h: f16 CSR-sorted rbf [nEdges][16] + pad
    unsigned short* x2b  = (unsigned short*)d_ws;
    unsigned short* blob = (unsigned short*)((char*)d_ws + 25690112);
    int* ibase   = (int*)((char*)d_ws + 26738688);
    int* counts  = ibase;                 // 65536
    int* offsets = ibase + 65536;         // 65536
    int* cursor  = ibase + 131072;        // 65536
    int* bsum    = ibase + 196608;        // 1024
    int* order   = ibase + 197632;        // nEdges
    __half* rbf_h = (__half*)((char*)d_ws + 31529216);

    zero_kernel<<<64, 256, 0, stream>>>(counts, 65536);

    wconv_kernel<<<56, 256, 0, stream>>>(W1, res_W, blob);

    hist_kernel<<<2048, 256, 0, stream>>>(id_j, counts, nEdges);
    int nb = (nAtoms + 1023) / 1024;
    scan_reduce<<<nb, 256, 0, stream>>>(counts, bsum, nAtoms);
    scan_sums<<<1, 64, 0, stream>>>(bsum, nb);
    scan_write<<<nb, 256, 0, stream>>>(counts, bsum, offsets, cursor, nAtoms);
    order_kernel<<<2048, 256, 0, stream>>>(id_j, cursor, order, rbf, rbf_h, nEdges);

    gather_kernel<<<nAtoms, 64, 0, stream>>>(m, rbf_h, order, offsets, counts,
                                             W_rbf, x2b);

    dense_kernel<<<nTiles, 512, 0, stream>>>(x2b, blob, scale, out, nAtoms);
}